// Round 2
// baseline (30.496 us; speedup 1.0000x reference)
//
#include <hip/hip_runtime.h>

// Volume rendering: M=65536 rays, N=128 samples/ray.
// One 64-lane wave per ray, 2 samples per lane.
// weights w_i = T_i - T_{i+1} where T_i = exp(-cumsum_{j<i} tau_j).
//
// NOTE: exclusive scan MUST be shfl_up(inclusive, 1), not (inclusive - local):
// lane 63's local pair-sum contains the terminal tau = density*1e10 (~2e10),
// which absorbs the finite prefix (ulp ~2048) -> v - psum == 0, corrupting T.

#define NSAMP 128

__global__ __launch_bounds__(256) void volrend_kernel(
    const float* __restrict__ density,   // [M,N]
    const float* __restrict__ feature,   // [M,N,3]
    const float* __restrict__ depth,     // [M,N]
    float* __restrict__ out,             // [M,4]
    int M)
{
    const int gtid = blockIdx.x * blockDim.x + threadIdx.x;
    const int ray  = gtid >> 6;          // one wave per ray
    const int lane = threadIdx.x & 63;
    if (ray >= M) return;

    const int s0 = 2 * lane;             // this lane's first sample

    // ---- coalesced vector loads ----
    const size_t rowN = (size_t)ray * NSAMP;
    float2 d2   = *(const float2*)(depth   + rowN + s0);   // depth[s0], depth[s0+1]
    float2 dens = *(const float2*)(density + rowN + s0);   // sigma[s0], sigma[s0+1]
    const float* fbase = feature + (size_t)ray * NSAMP * 3 + (size_t)s0 * 3;
    float2 fa = *(const float2*)(fbase + 0);   // f0.r f0.g
    float2 fb = *(const float2*)(fbase + 2);   // f0.b f1.r
    float2 fc = *(const float2*)(fbase + 4);   // f1.g f1.b

    // ---- deltas (terminal delta = 1e10) ----
    float next_x = __shfl_down(d2.x, 1, 64);   // depth[s0+2] from lane+1
    float delta0 = d2.y - d2.x;
    float delta1 = (lane == 63) ? 1e10f : (next_x - d2.y);

    float tau0 = dens.x * delta0;
    float tau1 = dens.y * delta1;
    float psum = tau0 + tau1;

    // ---- inclusive wave scan of pair-sums (6 shfl_up steps) ----
    float v = psum;
    #pragma unroll
    for (int off = 1; off < 64; off <<= 1) {
        float t = __shfl_up(v, off, 64);
        if (lane >= off) v += t;
    }
    // exact exclusive scan: previous lane's inclusive value (no cancellation)
    float excl = __shfl_up(v, 1, 64);
    if (lane == 0) excl = 0.0f;

    // cum at sample boundaries: c0 -> before s0, c1 -> before s0+1, c2 -> after
    float c0 = excl;
    float c1 = excl + tau0;
    float c2 = c1 + tau1;                      // lane 63: huge -> T2 = 0 exactly
    float T0 = __expf(-c0);
    float T1 = __expf(-c1);
    float T2 = __expf(-c2);
    float w0 = T0 - T1;                        // T_i * (1 - exp(-tau_i))
    float w1 = T1 - T2;

    // ---- weighted accumulation ----
    float r  = w0 * fa.x + w1 * fb.y;
    float g  = w0 * fa.y + w1 * fc.x;
    float b  = w0 * fb.x + w1 * fc.y;
    float dd = w0 * d2.x + w1 * d2.y;

    // ---- wave reduction (sum over 64 lanes) ----
    #pragma unroll
    for (int off = 32; off >= 1; off >>= 1) {
        r  += __shfl_down(r,  off, 64);
        g  += __shfl_down(g,  off, 64);
        b  += __shfl_down(b,  off, 64);
        dd += __shfl_down(dd, off, 64);
    }

    if (lane == 0) {
        *(float4*)(out + (size_t)ray * 4) = make_float4(r, g, b, dd);
    }
}

extern "C" void kernel_launch(void* const* d_in, const int* in_sizes, int n_in,
                              void* d_out, int out_size, void* d_ws, size_t ws_size,
                              hipStream_t stream) {
    const float* density = (const float*)d_in[0];   // [M,N,1]
    const float* feature = (const float*)d_in[1];   // [M,N,3]
    const float* depth   = (const float*)d_in[2];   // [M,N]
    float* out = (float*)d_out;

    const int M = in_sizes[2] / NSAMP;              // 65536

    const int threads = 256;                        // 4 waves = 4 rays / block
    const int raysPerBlock = threads / 64;
    const int blocks = (M + raysPerBlock - 1) / raysPerBlock;
    volrend_kernel<<<blocks, threads, 0, stream>>>(density, feature, depth, out, M);
}

// Round 3
// 29.637 us; speedup vs baseline: 1.0290x; 1.0290x over previous
//
#include <hip/hip_runtime.h>

// Volume rendering: M=65536 rays, N=128 samples/ray.
// 2 rays per 64-lane wave: 32 lanes/ray, 4 samples/lane -> all loads dwordx4.
// weights w_i = T_i - T_{i+1}, T_i = exp(-exclusive_cumsum(tau)).
//
// NOTE: exclusive scan MUST be shfl_up(inclusive, 1), not (inclusive - local):
// the terminal tau = density*1e10 (~2e10) absorbs the finite prefix in fp32.

#define NSAMP 128

__global__ __launch_bounds__(256) void volrend_kernel(
    const float* __restrict__ density,   // [M,N]
    const float* __restrict__ feature,   // [M,N,3]
    const float* __restrict__ depth,     // [M,N]
    float* __restrict__ out,             // [M,4]
    int M)
{
    const int tid     = blockIdx.x * blockDim.x + threadIdx.x;
    const int seg     = tid >> 5;          // one 32-lane segment per ray
    const int sublane = threadIdx.x & 31;
    const int ray     = seg;
    if (ray >= M) return;

    const int s0 = 4 * sublane;            // this lane's first sample

    // ---- coalesced 16B vector loads ----
    const size_t rowN = (size_t)ray * NSAMP;
    float4 d4   = *(const float4*)(depth   + rowN + s0);
    float4 dens = *(const float4*)(density + rowN + s0);
    const float* fbase = feature + (size_t)ray * NSAMP * 3 + (size_t)s0 * 3; // 48B/lane, 16B-aligned
    float4 f0 = *(const float4*)(fbase + 0);   // s0:rgb + s1:r
    float4 f1 = *(const float4*)(fbase + 4);   // s1:gb + s2:rg
    float4 f2 = *(const float4*)(fbase + 8);   // s2:b + s3:rgb

    // ---- deltas (terminal delta = 1e10) ----
    float next_x = __shfl_down(d4.x, 1, 32);   // depth[s0+4] from next lane in segment
    float delta0 = d4.y - d4.x;
    float delta1 = d4.z - d4.y;
    float delta2 = d4.w - d4.z;
    float delta3 = (sublane == 31) ? 1e10f : (next_x - d4.w);

    float tau0 = dens.x * delta0;
    float tau1 = dens.y * delta1;
    float tau2 = dens.z * delta2;
    float tau3 = dens.w * delta3;
    float psum = tau0 + tau1 + tau2 + tau3;

    // ---- inclusive segmented scan (width 32, 5 steps) ----
    float v = psum;
    #pragma unroll
    for (int off = 1; off < 32; off <<= 1) {
        float t = __shfl_up(v, off, 32);
        if (sublane >= off) v += t;
    }
    // exact exclusive scan: previous lane's inclusive value (no cancellation)
    float excl = __shfl_up(v, 1, 32);
    if (sublane == 0) excl = 0.0f;

    // cumulative optical depth at sample boundaries
    float c0 = excl;
    float c1 = c0 + tau0;
    float c2 = c1 + tau1;
    float c3 = c2 + tau2;
    float c4 = c3 + tau3;                      // lane 31: huge -> T4 = 0 exactly
    float T0 = __expf(-c0);
    float T1 = __expf(-c1);
    float T2 = __expf(-c2);
    float T3 = __expf(-c3);
    float T4 = __expf(-c4);
    float w0 = T0 - T1;
    float w1 = T1 - T2;
    float w2 = T2 - T3;
    float w3 = T3 - T4;

    // ---- weighted accumulation (4 samples) ----
    float r  = w0 * f0.x + w1 * f0.w + w2 * f1.z + w3 * f2.y;
    float g  = w0 * f0.y + w1 * f1.x + w2 * f1.w + w3 * f2.z;
    float b  = w0 * f0.z + w1 * f1.y + w2 * f2.x + w3 * f2.w;
    float dd = w0 * d4.x + w1 * d4.y + w2 * d4.z + w3 * d4.w;

    // ---- segmented reduction (width 32, 5 steps) ----
    #pragma unroll
    for (int off = 16; off >= 1; off >>= 1) {
        r  += __shfl_down(r,  off, 32);
        g  += __shfl_down(g,  off, 32);
        b  += __shfl_down(b,  off, 32);
        dd += __shfl_down(dd, off, 32);
    }

    if (sublane == 0) {
        *(float4*)(out + (size_t)ray * 4) = make_float4(r, g, b, dd);
    }
}

extern "C" void kernel_launch(void* const* d_in, const int* in_sizes, int n_in,
                              void* d_out, int out_size, void* d_ws, size_t ws_size,
                              hipStream_t stream) {
    const float* density = (const float*)d_in[0];   // [M,N,1]
    const float* feature = (const float*)d_in[1];   // [M,N,3]
    const float* depth   = (const float*)d_in[2];   // [M,N]
    float* out = (float*)d_out;

    const int M = in_sizes[2] / NSAMP;              // 65536

    const int threads = 256;                        // 8 rays / block (32 lanes each)
    const int raysPerBlock = threads / 32;
    const int blocks = (M + raysPerBlock - 1) / raysPerBlock;
    volrend_kernel<<<blocks, threads, 0, stream>>>(density, feature, depth, out, M);
}